// Round 1
// baseline (687.516 us; speedup 1.0000x reference)
//
#include <hip/hip_runtime.h>
#include <math.h>

#define GG 32
#define NN1 1024
#define FF 128
#define MAT (NN1*NN1)
#define KKEEP 32768
#define NBINS 4096
#define CAP 4096
#define TIECAP 64

__device__ __forceinline__ int binof(float v) {
    int b = (int)(v * (float)NBINS);
    b = b < 0 ? 0 : (b > NBINS - 1 ? NBINS - 1 : b);
    return b;
}

// ---------------- K1: per-G 4096-bin histogram over value bins ----------------
__global__ __launch_bounds__(256) void k_hist(const float* __restrict__ adj,
                                              unsigned* __restrict__ hist) {
    __shared__ unsigned lh[NBINS];
    int g = blockIdx.x >> 4, seg = blockIdx.x & 15;
    for (int i = threadIdx.x; i < NBINS; i += 256) lh[i] = 0;
    __syncthreads();
    const float4* p = (const float4*)(adj + (size_t)g * MAT + (size_t)seg * 65536);
    for (int i = threadIdx.x; i < 16384; i += 256) {
        float4 v = p[i];
        atomicAdd(&lh[binof(v.x)], 1u);
        atomicAdd(&lh[binof(v.y)], 1u);
        atomicAdd(&lh[binof(v.z)], 1u);
        atomicAdd(&lh[binof(v.w)], 1u);
    }
    __syncthreads();
    unsigned* gh = hist + g * NBINS;
    for (int i = threadIdx.x; i < NBINS; i += 256)
        if (lh[i]) atomicAdd(&gh[i], lh[i]);
}

// ---------------- K2: find threshold bin + needed count inside it ----------------
__global__ __launch_bounds__(256) void k_selbin(const unsigned* __restrict__ hist,
                                                unsigned* __restrict__ binSel,
                                                unsigned* __restrict__ needArr) {
    int g = blockIdx.x;
    __shared__ unsigned csum[256];
    __shared__ unsigned after[256];
    const unsigned* gh = hist + g * NBINS;
    int t = threadIdx.x;
    unsigned s = 0;
    for (int i = 0; i < 16; ++i) s += gh[t * 16 + i];
    csum[t] = s;
    __syncthreads();
    if (t == 0) {
        unsigned run = 0;
        for (int c = 255; c >= 0; --c) { after[c] = run; run += csum[c]; }
    }
    __syncthreads();
    if (after[t] < (unsigned)KKEEP && after[t] + csum[t] >= (unsigned)KKEEP) {
        unsigned cum = after[t];
        for (int b2 = t * 16 + 15; b2 >= t * 16; --b2) {
            unsigned h = gh[b2];
            cum += h;
            if (cum >= (unsigned)KKEEP) {
                binSel[g] = (unsigned)b2;
                needArr[g] = (unsigned)KKEEP - (cum - h);
                break;
            }
        }
    }
}

// ---------------- K3: gather candidates (value,index) in threshold bin ----------------
__global__ __launch_bounds__(256) void k_gather(const float* __restrict__ adj,
                                                const unsigned* __restrict__ binSel,
                                                uint2* __restrict__ cand,
                                                unsigned* __restrict__ candCount) {
    int g = blockIdx.x >> 4, seg = blockIdx.x & 15;
    unsigned bs = binSel[g];
    const float4* p = (const float4*)(adj + (size_t)g * MAT + (size_t)seg * 65536);
    uint2* cg = cand + (size_t)g * CAP;
    for (int i = threadIdx.x; i < 16384; i += 256) {
        float4 v = p[i];
        unsigned base = (unsigned)(seg * 65536 + i * 4);
        float vv[4] = {v.x, v.y, v.z, v.w};
#pragma unroll
        for (int d2 = 0; d2 < 4; ++d2) {
            if (binof(vv[d2]) == (int)bs) {
                unsigned pos = atomicAdd(&candCount[g], 1u);
                if (pos < CAP) {
                    cg[pos].x = __float_as_uint(vv[d2]);
                    cg[pos].y = base + (unsigned)d2;
                }
            }
        }
    }
}

// ---------------- K4: exact rank within bin -> threshold T + tie index list ----------------
__global__ __launch_bounds__(256) void k_rank(const uint2* __restrict__ cand,
                                              const unsigned* __restrict__ candCount,
                                              const unsigned* __restrict__ needArr,
                                              float* __restrict__ thr,
                                              unsigned* __restrict__ tieIdx,
                                              unsigned* __restrict__ tieCount) {
    int g = blockIdx.x;
    unsigned m = candCount[g];
    if (m > CAP) m = CAP;
    unsigned need = needArr[g];
    const uint2* cg = cand + (size_t)g * CAP;
    __shared__ float sT;
    unsigned rk[16];
    int nmine = 0;
    for (unsigned ci = threadIdx.x; ci < m; ci += 256) {
        float v = __uint_as_float(cg[ci].x);
        unsigned idx = cg[ci].y;
        unsigned r = 0;
        for (unsigned j2 = 0; j2 < m; ++j2) {
            float vj = __uint_as_float(cg[j2].x);
            if (vj > v || (vj == v && cg[j2].y < idx)) ++r;
        }
        rk[nmine++] = r;
        if (r == need - 1) sT = v;   // unique rank -> unique writer
    }
    __syncthreads();
    float T = sT;
    if (threadIdx.x == 0) thr[g] = T;
    int s2 = 0;
    for (unsigned ci = threadIdx.x; ci < m; ci += 256, ++s2) {
        float v = __uint_as_float(cg[ci].x);
        if (v == T && rk[s2] < need) {
            unsigned pos = atomicAdd(&tieCount[g], 1u);
            if (pos < TIECAP) tieIdx[g * TIECAP + pos] = cg[ci].y;
        }
    }
}

// keep predicate: exact top-k semantics (ties at T kept only if flat idx in tie list)
__device__ __forceinline__ float keepf(float v, unsigned idx, float T,
                                       const unsigned* __restrict__ tie, unsigned tc) {
    if (v > T) return v;
    if (v == T) {
        for (unsigned i = 0; i < tc; ++i)
            if (tie[i] == idx) return v;
    }
    return 0.f;
}

// ---------------- K5: masked symmetrize into d_out adj region + deg ----------------
__global__ __launch_bounds__(256) void k_sym(const float* __restrict__ adj,
                                             const float* __restrict__ thr,
                                             const unsigned* __restrict__ tieIdx,
                                             const unsigned* __restrict__ tieCount,
                                             float* __restrict__ sOut,
                                             float* __restrict__ deg) {
    __shared__ float Al[64 * 65];
    __shared__ float Bl[64 * 65];
    int g = blockIdx.x / 136;
    int pr = blockIdx.x % 136;
    int ti = 0, rem = pr;
    while (rem >= 16 - ti) { rem -= 16 - ti; ++ti; }
    int tj = ti + rem;
    int t = threadIdx.x;
    float T = thr[g];
    unsigned tc = tieCount[g];
    if (tc > TIECAP) tc = TIECAP;
    const unsigned* tie = tieIdx + g * TIECAP;
    const float* ag = adj + (size_t)g * MAT;
    float* sg = sOut + (size_t)g * MAT;
    float* dg = deg + g * NN1;
    int r0 = t >> 4;
    int c0 = (t & 15) << 2;
    int i0 = ti << 6, j0 = tj << 6;
    bool off = (ti != tj);
    float av[4][4], bv[4][4];
#pragma unroll
    for (int q = 0; q < 4; ++q) {
        int r = r0 + (q << 4);
        unsigned base = (unsigned)((i0 + r) * NN1 + j0 + c0);
        float4 v = *(const float4*)(ag + base);
        av[q][0] = keepf(v.x, base + 0, T, tie, tc);
        av[q][1] = keepf(v.y, base + 1, T, tie, tc);
        av[q][2] = keepf(v.z, base + 2, T, tie, tc);
        av[q][3] = keepf(v.w, base + 3, T, tie, tc);
        Al[r * 65 + c0 + 0] = av[q][0];
        Al[r * 65 + c0 + 1] = av[q][1];
        Al[r * 65 + c0 + 2] = av[q][2];
        Al[r * 65 + c0 + 3] = av[q][3];
    }
    if (off) {
#pragma unroll
        for (int q = 0; q < 4; ++q) {
            int r = r0 + (q << 4);
            unsigned base = (unsigned)((j0 + r) * NN1 + i0 + c0);
            float4 v = *(const float4*)(ag + base);
            bv[q][0] = keepf(v.x, base + 0, T, tie, tc);
            bv[q][1] = keepf(v.y, base + 1, T, tie, tc);
            bv[q][2] = keepf(v.z, base + 2, T, tie, tc);
            bv[q][3] = keepf(v.w, base + 3, T, tie, tc);
            Bl[r * 65 + c0 + 0] = bv[q][0];
            Bl[r * 65 + c0 + 1] = bv[q][1];
            Bl[r * 65 + c0 + 2] = bv[q][2];
            Bl[r * 65 + c0 + 3] = bv[q][3];
        }
    }
    __syncthreads();
#pragma unroll
    for (int q = 0; q < 4; ++q) {
        int r = r0 + (q << 4);
        const float* Tr = off ? Bl : Al;
        float s0 = 0.5f * (av[q][0] + Tr[(c0 + 0) * 65 + r]);
        float s1 = 0.5f * (av[q][1] + Tr[(c0 + 1) * 65 + r]);
        float s2 = 0.5f * (av[q][2] + Tr[(c0 + 2) * 65 + r]);
        float s3 = 0.5f * (av[q][3] + Tr[(c0 + 3) * 65 + r]);
        *(float4*)(sg + (size_t)(i0 + r) * NN1 + j0 + c0) = make_float4(s0, s1, s2, s3);
        float rs = s0 + s1 + s2 + s3;
        rs += __shfl_xor(rs, 1);
        rs += __shfl_xor(rs, 2);
        rs += __shfl_xor(rs, 4);
        rs += __shfl_xor(rs, 8);
        if ((t & 15) == 0) atomicAdd(&dg[i0 + r], rs);
    }
    if (off) {
#pragma unroll
        for (int q = 0; q < 4; ++q) {
            int r = r0 + (q << 4);
            float s0 = 0.5f * (bv[q][0] + Al[(c0 + 0) * 65 + r]);
            float s1 = 0.5f * (bv[q][1] + Al[(c0 + 1) * 65 + r]);
            float s2 = 0.5f * (bv[q][2] + Al[(c0 + 2) * 65 + r]);
            float s3 = 0.5f * (bv[q][3] + Al[(c0 + 3) * 65 + r]);
            *(float4*)(sg + (size_t)(j0 + r) * NN1 + i0 + c0) = make_float4(s0, s1, s2, s3);
            float rs = s0 + s1 + s2 + s3;
            rs += __shfl_xor(rs, 1);
            rs += __shfl_xor(rs, 2);
            rs += __shfl_xor(rs, 4);
            rs += __shfl_xor(rs, 8);
            if ((t & 15) == 0) atomicAdd(&dg[j0 + r], rs);
        }
    }
}

// ---------------- K6: dinv = deg>0 ? deg^-1/2 : 0 ----------------
__global__ __launch_bounds__(256) void k_dinv(const float* __restrict__ deg,
                                              float* __restrict__ dinv) {
    int i = blockIdx.x * 256 + threadIdx.x;
    float d = deg[i];
    dinv[i] = (d > 0.f) ? (float)(1.0 / sqrt((double)d)) : 0.f;
}

// ---------------- K7: fused dinv-scale (norm_adj write-back, in-place) + fp32 GEMM1
// agg = norm_adj @ x ; writes C = x + agg into hout region.
// One block per (g, 128-row panel). 256 thr, 8x8 micro-tile, Tk=32, sw-pipelined staging.
__global__ __launch_bounds__(256) void k_ng1(const float* __restrict__ x,
                                             const float* __restrict__ dinv,
                                             float* __restrict__ sadj,
                                             float* __restrict__ cout) {
    __shared__ float Alds[32 * 132];   // [kk][row], transposed
    __shared__ float Blds[32 * 132];   // [kk][f]
    int g = blockIdx.x >> 3;
    int I = (blockIdx.x & 7) << 7;
    int t = threadIdx.x;
    int ty = t >> 4, tx = t & 15;
    const float* xg = x + (size_t)g * NN1 * FF;
    float* sg = sadj + (size_t)g * MAT;
    const float* dv = dinv + g * NN1;
    float acc[8][8];
#pragma unroll
    for (int i = 0; i < 8; ++i)
#pragma unroll
        for (int j2 = 0; j2 < 8; ++j2) acc[i][j2] = 0.f;

    int aRow = t >> 3;           // 0..31, step 32 -> 128 rows
    int aCol = (t & 7) << 2;     // 0..28
    int bRow = t >> 5;           // 0..7, step 8 -> 32 rows
    int bCol = (t & 31) << 2;    // 0..124

    float diA[4];
#pragma unroll
    for (int s2 = 0; s2 < 4; ++s2) diA[s2] = dv[I + aRow + 32 * s2];

    float4 aR[4], bR[4];

#define LOAD_AB(k0)                                                              \
    {                                                                            \
        float4 dj = *(const float4*)(dv + (k0) + aCol);                          \
        _Pragma("unroll") for (int s2 = 0; s2 < 4; ++s2) {                       \
            int r = aRow + 32 * s2;                                              \
            float* p = sg + (size_t)(I + r) * NN1 + (k0) + aCol;                 \
            float4 v = *(const float4*)p;                                        \
            float di = diA[s2];                                                  \
            v.x *= di * dj.x; v.y *= di * dj.y;                                  \
            v.z *= di * dj.z; v.w *= di * dj.w;                                  \
            *(float4*)p = v;                                                     \
            aR[s2] = v;                                                          \
        }                                                                        \
        _Pragma("unroll") for (int s2 = 0; s2 < 4; ++s2) {                       \
            int r = bRow + 8 * s2;                                               \
            bR[s2] = *(const float4*)(xg + (size_t)((k0) + r) * FF + bCol);      \
        }                                                                        \
    }

    LOAD_AB(0);
    for (int ks = 0; ks < 32; ++ks) {
        // stage regs -> LDS
#pragma unroll
        for (int s2 = 0; s2 < 4; ++s2) {
            int r = aRow + 32 * s2;
            Alds[(aCol + 0) * 132 + r] = aR[s2].x;
            Alds[(aCol + 1) * 132 + r] = aR[s2].y;
            Alds[(aCol + 2) * 132 + r] = aR[s2].z;
            Alds[(aCol + 3) * 132 + r] = aR[s2].w;
        }
#pragma unroll
        for (int s2 = 0; s2 < 4; ++s2)
            *(float4*)(Blds + (bRow + 8 * s2) * 132 + bCol) = bR[s2];
        __syncthreads();
        if (ks < 31) LOAD_AB((ks + 1) << 5);
#pragma unroll
        for (int kk = 0; kk < 32; ++kk) {
            float4 a0 = *(const float4*)(Alds + kk * 132 + (ty << 3));
            float4 a1 = *(const float4*)(Alds + kk * 132 + (ty << 3) + 4);
            float4 b0 = *(const float4*)(Blds + kk * 132 + (tx << 3));
            float4 b1 = *(const float4*)(Blds + kk * 132 + (tx << 3) + 4);
            float a[8] = {a0.x, a0.y, a0.z, a0.w, a1.x, a1.y, a1.z, a1.w};
            float b[8] = {b0.x, b0.y, b0.z, b0.w, b1.x, b1.y, b1.z, b1.w};
#pragma unroll
            for (int i = 0; i < 8; ++i)
#pragma unroll
                for (int j2 = 0; j2 < 8; ++j2) acc[i][j2] += a[i] * b[j2];
        }
        __syncthreads();
    }
#undef LOAD_AB
    float* cg = cout + (size_t)g * NN1 * FF;
#pragma unroll
    for (int i = 0; i < 8; ++i) {
        int r = I + (ty << 3) + i;
        const float* xp = xg + (size_t)r * FF + (tx << 3);
        float4 x0 = *(const float4*)xp;
        float4 x1 = *(const float4*)(xp + 4);
        float* op = cg + (size_t)r * FF + (tx << 3);
        *(float4*)op = make_float4(acc[i][0] + x0.x, acc[i][1] + x0.y,
                                   acc[i][2] + x0.z, acc[i][3] + x0.w);
        *(float4*)(op + 4) = make_float4(acc[i][4] + x1.x, acc[i][5] + x1.y,
                                         acc[i][6] + x1.z, acc[i][7] + x1.w);
    }
}

// ---------------- K8: h = gelu(C @ W + b) in place over hout ----------------
__global__ __launch_bounds__(256) void k_gemm2(const float* __restrict__ W,
                                               const float* __restrict__ bias,
                                               float* __restrict__ hbuf) {
    __shared__ float Cl[64 * 129];
    __shared__ float Wl[32 * 128];
    int t = threadIdx.x;
    int ty = t >> 4, tx = t & 15;
    float* src = hbuf + (size_t)blockIdx.x * 64 * FF;
#pragma unroll
    for (int s2 = 0; s2 < 8; ++s2) {
        int r = (t >> 5) + 8 * s2;
        int c = (t & 31) << 2;
        float4 v = *(const float4*)(src + (size_t)r * FF + c);
        Cl[r * 129 + c + 0] = v.x;
        Cl[r * 129 + c + 1] = v.y;
        Cl[r * 129 + c + 2] = v.z;
        Cl[r * 129 + c + 3] = v.w;
    }
    float acc[4][8];
#pragma unroll
    for (int i = 0; i < 4; ++i)
#pragma unroll
        for (int j2 = 0; j2 < 8; ++j2) acc[i][j2] = 0.f;
    for (int ch = 0; ch < 4; ++ch) {
        __syncthreads();
#pragma unroll
        for (int s2 = 0; s2 < 4; ++s2) {
            int r = (t >> 5) + 8 * s2;
            int c = (t & 31) << 2;
            *(float4*)(Wl + r * 128 + c) =
                *(const float4*)(W + (size_t)((ch << 5) + r) * 128 + c);
        }
        __syncthreads();
#pragma unroll
        for (int kk = 0; kk < 32; ++kk) {
            int f = (ch << 5) + kk;
            float a[4];
#pragma unroll
            for (int i = 0; i < 4; ++i) a[i] = Cl[(4 * ty + i) * 129 + f];
            float4 b0 = *(const float4*)(Wl + kk * 128 + (tx << 3));
            float4 b1 = *(const float4*)(Wl + kk * 128 + (tx << 3) + 4);
            float b[8] = {b0.x, b0.y, b0.z, b0.w, b1.x, b1.y, b1.z, b1.w};
#pragma unroll
            for (int i = 0; i < 4; ++i)
#pragma unroll
                for (int j2 = 0; j2 < 8; ++j2) acc[i][j2] += a[i] * b[j2];
        }
    }
    float4 bb0 = *(const float4*)(bias + (tx << 3));
    float4 bb1 = *(const float4*)(bias + (tx << 3) + 4);
    float bb[8] = {bb0.x, bb0.y, bb0.z, bb0.w, bb1.x, bb1.y, bb1.z, bb1.w};
#pragma unroll
    for (int i = 0; i < 4; ++i) {
        int r = 4 * ty + i;
        float o[8];
#pragma unroll
        for (int j2 = 0; j2 < 8; ++j2) {
            float v = acc[i][j2] + bb[j2];
            o[j2] = 0.5f * v * (1.0f + erff(v * 0.70710678118654752f));
        }
        float* op = src + (size_t)r * FF + (tx << 3);
        *(float4*)op = make_float4(o[0], o[1], o[2], o[3]);
        *(float4*)(op + 4) = make_float4(o[4], o[5], o[6], o[7]);
    }
}

extern "C" void kernel_launch(void* const* d_in, const int* in_sizes, int n_in,
                              void* d_out, int out_size, void* d_ws, size_t ws_size,
                              hipStream_t stream) {
    const float* x = (const float*)d_in[0];
    const float* adj = (const float*)d_in[1];
    const float* W = (const float*)d_in[2];
    const float* b = (const float*)d_in[3];
    float* out = (float*)d_out;
    float* hout = out;                            // [G*N, 128]
    float* adjn = out + (size_t)GG * NN1 * FF;    // [G, N, N] (s, then norm in place)

    char* ws = (char*)d_ws;
    unsigned* hist      = (unsigned*)(ws);                 // 524288 B
    unsigned* candCount = (unsigned*)(ws + 524288);        // 128 B
    unsigned* tieCount  = (unsigned*)(ws + 524416);        // 128 B
    float*    deg       = (float*)(ws + 524544);           // 131072 B -> 655616
    unsigned* binSel    = (unsigned*)(ws + 655616);        // 128 B
    unsigned* needArr   = (unsigned*)(ws + 655744);        // 128 B
    float*    thr       = (float*)(ws + 655872);           // 128 B
    unsigned* tieIdx    = (unsigned*)(ws + 656000);        // 8192 B -> 664192
    uint2*    cand      = (uint2*)(ws + 664192);           // 1048576 B -> 1712768
    float*    dinv      = (float*)(ws + 1712768);          // 131072 B -> 1843840

    hipMemsetAsync(d_ws, 0, 655616, stream);               // hist+counts+deg

    k_hist<<<512, 256, 0, stream>>>(adj, hist);
    k_selbin<<<32, 256, 0, stream>>>(hist, binSel, needArr);
    k_gather<<<512, 256, 0, stream>>>(adj, binSel, cand, candCount);
    k_rank<<<32, 256, 0, stream>>>(cand, candCount, needArr, thr, tieIdx, tieCount);
    k_sym<<<GG * 136, 256, 0, stream>>>(adj, thr, tieIdx, tieCount, adjn, deg);
    k_dinv<<<128, 256, 0, stream>>>(deg, dinv);
    k_ng1<<<GG * 8, 256, 0, stream>>>(x, dinv, adjn, hout);
    k_gemm2<<<512, 256, 0, stream>>>(W, b, hout);
}